// Round 4
// baseline (35.405 us; speedup 1.0000x reference)
//
#include <hip/hip_runtime.h>

// velocity = MLP(concat[zone_embedding, person_attrs, time_vec])
// GCN layers in the reference are dead code (outputs unused) -> skipped.
//
// Round-4 change: __launch_bounds__(BLK, 2). Round-3 profiling showed
// VGPR_Count pinned at 52 = the allocator budgeting for ~10 waves/EU
// occupancy, while the launch is grid-limited to ~1.5 waves/EU
// (391 blocks x 4 waves / 1024 SIMDs). The kernel needs ~150 floats live
// (e[32]+h1[64]+h2[32]+addr temps) -> everything above 52 was spilled to
// scratch (L2-absorbed, invisible in HBM counters; VALUBusy stuck at 17%).
// min-waves-per-EU=2 raises the VGPR budget to 256: registers for free.

#define BLK 256

__global__ __launch_bounds__(BLK, 2) void zone_velocity_kernel(
    const float* __restrict__ t,
    const float* __restrict__ emb,      // [N,32]
    const float* __restrict__ pa,       // [8]
    const float* __restrict__ Wt1,      // [1,16]
    const float* __restrict__ bt1,      // [16]
    const float* __restrict__ Wt2,      // [16,16]
    const float* __restrict__ bt2,      // [16]
    const float* __restrict__ Wd1,      // [56,64]
    const float* __restrict__ bd1,      // [64]
    const float* __restrict__ Wd2,      // [64,32]
    const float* __restrict__ bd2,      // [32]
    const float* __restrict__ Wd3,      // [32,32]
    const float* __restrict__ bd3,      // [32]
    float* __restrict__ out,            // [N,32]
    int N)
{
    __shared__ float s_u[16];   // relu(t*Wt1+bt1)
    __shared__ float s_tv[16];  // time_vec
    __shared__ float s_h1b[64]; // bd1 + (person|time) @ Wd1[32:56]

    const int tidx = threadIdx.x;

    // ---- time encoder (tiny; 16 lanes) ----
    const float tval = t[0];
    if (tidx < 16) s_u[tidx] = fmaxf(tval * Wt1[tidx] + bt1[tidx], 0.0f);
    __syncthreads();
    if (tidx < 16) {
        float acc = bt2[tidx];
        #pragma unroll
        for (int k = 0; k < 16; k++) acc = fmaf(s_u[k], Wt2[k * 16 + tidx], acc);
        s_tv[tidx] = acc;  // no relu on second time layer
    }
    __syncthreads();

    // ---- h1 base: bd1 + person/time contributions (zone-uniform) ----
    if (tidx < 64) {
        float acc = bd1[tidx];
        #pragma unroll
        for (int k = 0; k < 8; k++)
            acc = fmaf(pa[k], Wd1[(32 + k) * 64 + tidx], acc);
        #pragma unroll
        for (int k = 0; k < 16; k++)
            acc = fmaf(s_tv[k], Wd1[(40 + k) * 64 + tidx], acc);
        s_h1b[tidx] = acc;
    }
    __syncthreads();

    const int i = blockIdx.x * BLK + tidx;
    if (i >= N) return;

    // ---- h1 base into registers (broadcast LDS reads) ----
    float h1[64];
    #pragma unroll
    for (int j = 0; j < 64; j++) h1[j] = s_h1b[j];

    // ---- load this zone's embedding (vectorized, coalesced) ----
    float e[32];
    const float4* e4 = reinterpret_cast<const float4*>(emb + (size_t)i * 32);
    #pragma unroll
    for (int q = 0; q < 8; q++) {
        float4 v = e4[q];
        e[4 * q + 0] = v.x; e[4 * q + 1] = v.y;
        e[4 * q + 2] = v.z; e[4 * q + 3] = v.w;
    }

    // ---- layer 1: h1[64] += e @ Wd1[0:32]; relu ----
    // FULL unroll: constant indices -> e/h1 in VGPRs, Wd1 via s_load/SGPR.
    #pragma unroll
    for (int k = 0; k < 32; k++) {
        const float c = e[k];
        #pragma unroll
        for (int j = 0; j < 64; j++)
            h1[j] = fmaf(c, Wd1[k * 64 + j], h1[j]);
    }
    #pragma unroll
    for (int j = 0; j < 64; j++) h1[j] = fmaxf(h1[j], 0.0f);

    // ---- layer 2: h2[32] = relu(h1 @ Wd2 + bd2) ----
    float h2[32];
    #pragma unroll
    for (int j = 0; j < 32; j++) h2[j] = bd2[j];
    #pragma unroll
    for (int k = 0; k < 64; k++) {
        const float c = h1[k];
        #pragma unroll
        for (int j = 0; j < 32; j++)
            h2[j] = fmaf(c, Wd2[k * 32 + j], h2[j]);
    }
    #pragma unroll
    for (int j = 0; j < 32; j++) h2[j] = fmaxf(h2[j], 0.0f);

    // ---- layer 3: out = h2 @ Wd3 + bd3 ----
    float o[32];
    #pragma unroll
    for (int j = 0; j < 32; j++) o[j] = bd3[j];
    #pragma unroll
    for (int k = 0; k < 32; k++) {
        const float c = h2[k];
        #pragma unroll
        for (int j = 0; j < 32; j++)
            o[j] = fmaf(c, Wd3[k * 32 + j], o[j]);
    }

    // ---- coalesced store ----
    float4* o4 = reinterpret_cast<float4*>(out + (size_t)i * 32);
    #pragma unroll
    for (int q = 0; q < 8; q++) {
        float4 v;
        v.x = o[4 * q + 0]; v.y = o[4 * q + 1];
        v.z = o[4 * q + 2]; v.w = o[4 * q + 3];
        o4[q] = v;
    }
}

extern "C" void kernel_launch(void* const* d_in, const int* in_sizes, int n_in,
                              void* d_out, int out_size, void* d_ws, size_t ws_size,
                              hipStream_t stream) {
    // setup_inputs() order:
    //  0 t, 1 zone_embedding, 2 zone_features, 3 person_attrs, 4 edge_index,
    //  5 W1, 6 b1, 7 W2, 8 b2, 9 Wt1, 10 bt1, 11 Wt2, 12 bt2,
    // 13 Wd1, 14 bd1, 15 Wd2, 16 bd2, 17 Wd3, 18 bd3
    const float* t   = (const float*)d_in[0];
    const float* emb = (const float*)d_in[1];
    const float* pa  = (const float*)d_in[3];
    const float* Wt1 = (const float*)d_in[9];
    const float* bt1 = (const float*)d_in[10];
    const float* Wt2 = (const float*)d_in[11];
    const float* bt2 = (const float*)d_in[12];
    const float* Wd1 = (const float*)d_in[13];
    const float* bd1 = (const float*)d_in[14];
    const float* Wd2 = (const float*)d_in[15];
    const float* bd2 = (const float*)d_in[16];
    const float* Wd3 = (const float*)d_in[17];
    const float* bd3 = (const float*)d_in[18];

    const int N = in_sizes[1] / 32;  // 100000
    float* out = (float*)d_out;

    const int blocks = (N + BLK - 1) / BLK;
    zone_velocity_kernel<<<blocks, BLK, 0, stream>>>(
        t, emb, pa, Wt1, bt1, Wt2, bt2,
        Wd1, bd1, Wd2, bd2, Wd3, bd3, out, N);
}

// Round 5
// 15.563 us; speedup vs baseline: 2.2749x; 2.2749x over previous
//
#include <hip/hip_runtime.h>
#include <hip/hip_bf16.h>

// velocity = MLP(concat[zone_embedding, person_attrs, time_vec])
// GCN layers in the reference are dead code (outputs unused) -> skipped.
//
// Round-5: bf16 MFMA formulation. Rounds 1-4 showed the scalar-FMA version
// pinned at VALUBusy~17% regardless of weight path (LDS pipe / scratch /
// s_load): one weight fetch per FMA cannot be hidden at 1.5 waves/SIMD.
// MFMA puts weights in per-lane register fragments loaded ONCE (40 VGPRs),
// eliminating per-FMA weight traffic entirely.
//
// Per wave: 16-zone tile, 10 x mfma_f32_16x16x32_bf16 (4 + 2x2 + 2).
// Inter-layer re-fragmentation via per-wave LDS tiles (bf16, padded strides
// 72/40 bf16 -> <=2-way bank aliasing = free). Only HW layout assumed is the
// verified C/D map: col=lane&15, row=(lane>>4)*4+reg. A/B k-indexing k=8g+j
// is applied identically to both operands -> correct under any internal
// slot->k routing (k-sum is reindex-invariant). Bias/person/time folded into
// fp32 C-init (exact).

typedef __attribute__((ext_vector_type(8))) short bf16x8;
typedef __attribute__((ext_vector_type(4))) float f32x4;

#define BLK 256
#define WPB 4              // waves per block
#define H1_STRIDE 72       // bf16 elems per row: 64 + 8 pad (bank spread)
#define H2_STRIDE 40       // 32 + 8 pad

__device__ __forceinline__ short f2bf(float x) {
    union { __hip_bfloat16 h; short s; } u;
    u.h = __float2bfloat16(x);
    return u.s;
}

__global__ __launch_bounds__(BLK, 3) void zone_velocity_mfma(
    const float* __restrict__ tp,
    const float* __restrict__ emb,      // [N,32]
    const float* __restrict__ pa,       // [8]
    const float* __restrict__ Wt1, const float* __restrict__ bt1,
    const float* __restrict__ Wt2, const float* __restrict__ bt2,
    const float* __restrict__ Wd1, const float* __restrict__ bd1,  // [56,64],[64]
    const float* __restrict__ Wd2, const float* __restrict__ bd2,  // [64,32],[32]
    const float* __restrict__ Wd3, const float* __restrict__ bd3,  // [32,32],[32]
    float* __restrict__ out,            // [N,32]
    int N, int ntiles)
{
    __shared__ float s_u[16];
    __shared__ float s_tv[16];
    __shared__ float s_h1b[64];
    __shared__ __align__(16) short s_H1[WPB][16 * H1_STRIDE];
    __shared__ __align__(16) short s_H2[WPB][16 * H2_STRIDE];

    const int tidx = threadIdx.x;
    const int wave = tidx >> 6;
    const int lane = tidx & 63;
    const int c = lane & 15;   // A-row / B-col / D-col index
    const int g = lane >> 4;   // k-group (k = 8g + j)

    // ---- time encoder (fp32 exact) ----
    const float tval = tp[0];
    if (tidx < 16) s_u[tidx] = fmaxf(tval * Wt1[tidx] + bt1[tidx], 0.0f);
    __syncthreads();
    if (tidx < 16) {
        float a = bt2[tidx];
        #pragma unroll
        for (int k = 0; k < 16; k++) a = fmaf(s_u[k], Wt2[k * 16 + tidx], a);
        s_tv[tidx] = a;  // no relu on second time layer
    }
    __syncthreads();

    // ---- h1 base: bd1 + person/time @ Wd1[32:56] (zone-uniform, fp32) ----
    if (tidx < 64) {
        float a = bd1[tidx];
        #pragma unroll
        for (int k = 0; k < 8; k++)
            a = fmaf(pa[k], Wd1[(32 + k) * 64 + tidx], a);
        #pragma unroll
        for (int k = 0; k < 16; k++)
            a = fmaf(s_tv[k], Wd1[(40 + k) * 64 + tidx], a);
        s_h1b[tidx] = a;
    }
    __syncthreads();

    // ---- per-lane biases ----
    float h1b[4];
    #pragma unroll
    for (int tt = 0; tt < 4; tt++) h1b[tt] = s_h1b[16 * tt + c];
    float b2r[2] = { bd2[c], bd2[16 + c] };
    float b3r[2] = { bd3[c], bd3[16 + c] };

    // ---- weight fragments (loaded once; k = 8g + j on BOTH operands) ----
    bf16x8 w1f[4];        // Wd1[0:32] -> 4 n-tiles
    bf16x8 w2f[2][2];     // Wd2: 2 k-steps x 2 n-tiles
    bf16x8 w3f[2];        // Wd3: 2 n-tiles
    #pragma unroll
    for (int tt = 0; tt < 4; tt++)
        #pragma unroll
        for (int j = 0; j < 8; j++)
            w1f[tt][j] = f2bf(Wd1[(8 * g + j) * 64 + 16 * tt + c]);
    #pragma unroll
    for (int s = 0; s < 2; s++)
        #pragma unroll
        for (int tt = 0; tt < 2; tt++)
            #pragma unroll
            for (int j = 0; j < 8; j++)
                w2f[s][tt][j] = f2bf(Wd2[(32 * s + 8 * g + j) * 32 + 16 * tt + c]);
    #pragma unroll
    for (int tt = 0; tt < 2; tt++)
        #pragma unroll
        for (int j = 0; j < 8; j++)
            w3f[tt][j] = f2bf(Wd3[(8 * g + j) * 32 + 16 * tt + c]);

    short* H1 = s_H1[wave];
    short* H2 = s_H2[wave];

    const int wid = blockIdx.x * WPB + wave;
    const int nw  = gridDim.x * WPB;

    for (int tile = wid; tile < ntiles; tile += nw) {
        const int zb = tile * 16;

        // ---- X fragment: row = c (zone), k = 8g+j (emb channel) ----
        const int zr  = zb + c;
        const int zrc = (zr < N) ? zr : (N - 1);
        const float* ep = emb + (size_t)zrc * 32 + 8 * g;
        float4 xa = *reinterpret_cast<const float4*>(ep);
        float4 xb = *reinterpret_cast<const float4*>(ep + 4);
        bf16x8 af;
        af[0] = f2bf(xa.x); af[1] = f2bf(xa.y); af[2] = f2bf(xa.z); af[3] = f2bf(xa.w);
        af[4] = f2bf(xb.x); af[5] = f2bf(xb.y); af[6] = f2bf(xb.z); af[7] = f2bf(xb.w);

        // ---- layer 1: H1[16,64] = relu(X @ Wd1[0:32] + h1b) ----
        f32x4 acc1[4];
        #pragma unroll
        for (int tt = 0; tt < 4; tt++) {
            f32x4 ci; ci[0] = ci[1] = ci[2] = ci[3] = h1b[tt];
            acc1[tt] = __builtin_amdgcn_mfma_f32_16x16x32_bf16(af, w1f[tt], ci, 0, 0, 0);
        }
        // relu -> LDS (D map: row m = 4g+r, col n = 16tt+c)
        #pragma unroll
        for (int tt = 0; tt < 4; tt++)
            #pragma unroll
            for (int r = 0; r < 4; r++)
                H1[(4 * g + r) * H1_STRIDE + 16 * tt + c] =
                    f2bf(fmaxf(acc1[tt][r], 0.0f));

        __builtin_amdgcn_wave_barrier();
        asm volatile("s_waitcnt lgkmcnt(0)" ::: "memory");
        __builtin_amdgcn_sched_barrier(0);

        // ---- layer 2: H2[16,32] = relu(H1 @ Wd2 + bd2), K=64 in 2 steps ----
        f32x4 acc2[2];
        #pragma unroll
        for (int tt = 0; tt < 2; tt++) {
            f32x4 ci; ci[0] = ci[1] = ci[2] = ci[3] = b2r[tt];
            acc2[tt] = ci;
        }
        #pragma unroll
        for (int s = 0; s < 2; s++) {
            bf16x8 a2 = *reinterpret_cast<const bf16x8*>(
                H1 + c * H1_STRIDE + 32 * s + 8 * g);   // row=c, k=32s+8g+j
            #pragma unroll
            for (int tt = 0; tt < 2; tt++)
                acc2[tt] = __builtin_amdgcn_mfma_f32_16x16x32_bf16(
                    a2, w2f[s][tt], acc2[tt], 0, 0, 0);
        }
        #pragma unroll
        for (int tt = 0; tt < 2; tt++)
            #pragma unroll
            for (int r = 0; r < 4; r++)
                H2[(4 * g + r) * H2_STRIDE + 16 * tt + c] =
                    f2bf(fmaxf(acc2[tt][r], 0.0f));

        __builtin_amdgcn_wave_barrier();
        asm volatile("s_waitcnt lgkmcnt(0)" ::: "memory");
        __builtin_amdgcn_sched_barrier(0);

        // ---- layer 3: O[16,32] = H2 @ Wd3 + bd3 ----
        bf16x8 a3 = *reinterpret_cast<const bf16x8*>(H2 + c * H2_STRIDE + 8 * g);
        f32x4 acc3[2];
        #pragma unroll
        for (int tt = 0; tt < 2; tt++) {
            f32x4 ci; ci[0] = ci[1] = ci[2] = ci[3] = b3r[tt];
            acc3[tt] = __builtin_amdgcn_mfma_f32_16x16x32_bf16(a3, w3f[tt], ci, 0, 0, 0);
        }

        // ---- store: zone = zb + 4g + r, channel = 16tt + c ----
        #pragma unroll
        for (int r = 0; r < 4; r++) {
            const int zo = zb + 4 * g + r;
            if (zo < N) {
                float* op = out + (size_t)zo * 32;
                op[c]      = acc3[0][r];
                op[16 + c] = acc3[1][r];
            }
        }
    }
}

extern "C" void kernel_launch(void* const* d_in, const int* in_sizes, int n_in,
                              void* d_out, int out_size, void* d_ws, size_t ws_size,
                              hipStream_t stream) {
    // setup_inputs() order:
    //  0 t, 1 zone_embedding, 2 zone_features, 3 person_attrs, 4 edge_index,
    //  5 W1, 6 b1, 7 W2, 8 b2, 9 Wt1, 10 bt1, 11 Wt2, 12 bt2,
    // 13 Wd1, 14 bd1, 15 Wd2, 16 bd2, 17 Wd3, 18 bd3
    const float* t   = (const float*)d_in[0];
    const float* emb = (const float*)d_in[1];
    const float* pa  = (const float*)d_in[3];
    const float* Wt1 = (const float*)d_in[9];
    const float* bt1 = (const float*)d_in[10];
    const float* Wt2 = (const float*)d_in[11];
    const float* bt2 = (const float*)d_in[12];
    const float* Wd1 = (const float*)d_in[13];
    const float* bd1 = (const float*)d_in[14];
    const float* Wd2 = (const float*)d_in[15];
    const float* bd2 = (const float*)d_in[16];
    const float* Wd3 = (const float*)d_in[17];
    const float* bd3 = (const float*)d_in[18];

    const int N = in_sizes[1] / 32;          // 100000
    const int ntiles = (N + 15) / 16;        // 6250
    float* out = (float*)d_out;

    // 782 blocks x 4 waves = 3128 waves, ~2 tiles/wave, ~3 blocks/CU
    const int blocks = 782;
    zone_velocity_mfma<<<blocks, BLK, 0, stream>>>(
        t, emb, pa, Wt1, bt1, Wt2, bt2,
        Wd1, bd1, Wd2, bd2, Wd3, bd3, out, N, ntiles);
}